// Round 1
// baseline (456.596 us; speedup 1.0000x reference)
//
#include <hip/hip_runtime.h>
#include <hip/hip_bf16.h>

// TimeFeatureEmbedding: y[b,t,d] = sum_e x[b,t,e]*W[d,e] + b[d], then
// broadcast to [B,T,S,D]. D_MODEL=512, D_INP=4. Pure store-BW-bound:
// ~403 MB of float32 writes, inputs negligible.

#define D_MODEL 512
#define D_INP   4

__global__ __launch_bounds__(256) void tfe_embed_bcast(
    const float* __restrict__ x,   // [BT, 4]
    const float* __restrict__ W,   // [512, 4] row-major
    const float* __restrict__ bias,// [512]
    float* __restrict__ out,       // [BT, S, 512]
    int S)
{
    const int bt   = blockIdx.x;        // one block per (b,t)
    const int tid  = threadIdx.x;       // 256 threads
    const int d4   = tid & 127;         // float4 index within 512-wide row
    const int shalf= tid >> 7;          // 0 or 1: which half of s-values

    // x[b,t,0..3] — same for whole block, L1-broadcast
    const float4 xv = ((const float4*)x)[bt];

    // W rows d = 4*d4 .. 4*d4+3, each row is a float4 (D_INP=4)
    const float4* Wv = (const float4*)W;
    const float4 w0 = Wv[4 * d4 + 0];
    const float4 w1 = Wv[4 * d4 + 1];
    const float4 w2 = Wv[4 * d4 + 2];
    const float4 w3 = Wv[4 * d4 + 3];
    const float4 bv = ((const float4*)bias)[d4];

    float4 y;
    y.x = fmaf(xv.x, w0.x, fmaf(xv.y, w0.y, fmaf(xv.z, w0.z, fmaf(xv.w, w0.w, bv.x))));
    y.y = fmaf(xv.x, w1.x, fmaf(xv.y, w1.y, fmaf(xv.z, w1.z, fmaf(xv.w, w1.w, bv.y))));
    y.z = fmaf(xv.x, w2.x, fmaf(xv.y, w2.y, fmaf(xv.z, w2.z, fmaf(xv.w, w2.w, bv.z))));
    y.w = fmaf(xv.x, w3.x, fmaf(xv.y, w3.y, fmaf(xv.z, w3.z, fmaf(xv.w, w3.w, bv.w))));

    // Broadcast-store: row (b,t,s) is 512 floats = 128 float4.
    // Threads 0..127 and 128..255 handle alternating s values.
    float4* orow = (float4*)out + (size_t)bt * (size_t)S * 128;
    for (int si = shalf; si < S; si += 2) {
        orow[(size_t)si * 128 + d4] = y;
    }
}

extern "C" void kernel_launch(void* const* d_in, const int* in_sizes, int n_in,
                              void* d_out, int out_size, void* d_ws, size_t ws_size,
                              hipStream_t stream) {
    const float* x    = (const float*)d_in[0];   // [B,T,4] fp32
    // d_in[1] is S as a device scalar; derive S from sizes instead (no readback)
    const float* W    = (const float*)d_in[2];   // [512,4] fp32
    const float* bias = (const float*)d_in[3];   // [512] fp32
    float* out        = (float*)d_out;

    const int BT = in_sizes[0] / D_INP;               // 32*96 = 3072
    const int S  = out_size / (BT * D_MODEL);         // 64

    tfe_embed_bcast<<<BT, 256, 0, stream>>>(x, W, bias, out, S);
}

// Round 2
// 402.657 us; speedup vs baseline: 1.1340x; 1.1340x over previous
//
#include <hip/hip_runtime.h>
#include <hip/hip_bf16.h>

// TimeFeatureEmbedding: y[b,t,d] = sum_e x[b,t,e]*W[d,e] + b[d], broadcast
// to [B,T,S,D]. D=512, d_inp=4, S=64. Output 402.7 MB fp32 -> pure
// store-BW-bound. R1 post-mortem: per-block contiguous 128KB regions gave
// only ~2 TB/s (thousands of scattered write streams -> DRAM page thrash);
// the harness's own fillBuffer hits 6.2 TB/s with a flat grid-stride
// pattern. This kernel mirrors that pattern exactly.

#define D_MODEL 512
#define D_INP   4

// Flat grid-stride store kernel. stride (= gridDim*256) is chosen divisible
// by S*128, so each thread's (s, d4) is invariant across iterations:
// W rows + bias live in registers, only bt changes per iteration.
__global__ __launch_bounds__(256) void tfe_flat(
    const float4* __restrict__ x4,   // [BT]     x rows as float4 (d_inp=4)
    const float4* __restrict__ W4,   // [512]    each W row is one float4
    const float4* __restrict__ b4,   // [128]    bias as float4
    float4* __restrict__ out4,       // [N4]     flat output as float4
    size_t N4, int btShift)          // btShift = log2(S*128)
{
    const size_t stride = (size_t)gridDim.x * blockDim.x;
    size_t f = (size_t)blockIdx.x * blockDim.x + threadIdx.x;
    const int d4 = (int)(f & 127);   // constant: stride % 128 == 0

    const float4 w0 = W4[4 * d4 + 0];
    const float4 w1 = W4[4 * d4 + 1];
    const float4 w2 = W4[4 * d4 + 2];
    const float4 w3 = W4[4 * d4 + 3];
    const float4 bv = b4[d4];

    for (; f < N4; f += stride) {
        const int bt = (int)(f >> btShift);     // wave-uniform
        const float4 xv = x4[bt];               // 16B L2-hit broadcast
        float4 y;
        y.x = fmaf(xv.x, w0.x, fmaf(xv.y, w0.y, fmaf(xv.z, w0.z, fmaf(xv.w, w0.w, bv.x))));
        y.y = fmaf(xv.x, w1.x, fmaf(xv.y, w1.y, fmaf(xv.z, w1.z, fmaf(xv.w, w1.w, bv.y))));
        y.z = fmaf(xv.x, w2.x, fmaf(xv.y, w2.y, fmaf(xv.z, w2.z, fmaf(xv.w, w2.w, bv.z))));
        y.w = fmaf(xv.x, w3.x, fmaf(xv.y, w3.y, fmaf(xv.z, w3.z, fmaf(xv.w, w3.w, bv.w))));
        out4[f] = y;                            // consecutive lanes -> 1KB/wave store
    }
}

// Fallback for non-pow2 S (not hit with S=64): R1's block-per-(b,t) kernel.
__global__ __launch_bounds__(256) void tfe_embed_bcast(
    const float* __restrict__ x, const float* __restrict__ W,
    const float* __restrict__ bias, float* __restrict__ out, int S)
{
    const int bt = blockIdx.x;
    const int tid = threadIdx.x;
    const int d4 = tid & 127;
    const int shalf = tid >> 7;
    const float4 xv = ((const float4*)x)[bt];
    const float4* Wv = (const float4*)W;
    const float4 w0 = Wv[4 * d4 + 0];
    const float4 w1 = Wv[4 * d4 + 1];
    const float4 w2 = Wv[4 * d4 + 2];
    const float4 w3 = Wv[4 * d4 + 3];
    const float4 bv = ((const float4*)bias)[d4];
    float4 y;
    y.x = fmaf(xv.x, w0.x, fmaf(xv.y, w0.y, fmaf(xv.z, w0.z, fmaf(xv.w, w0.w, bv.x))));
    y.y = fmaf(xv.x, w1.x, fmaf(xv.y, w1.y, fmaf(xv.z, w1.z, fmaf(xv.w, w1.w, bv.y))));
    y.z = fmaf(xv.x, w2.x, fmaf(xv.y, w2.y, fmaf(xv.z, w2.z, fmaf(xv.w, w2.w, bv.z))));
    y.w = fmaf(xv.x, w3.x, fmaf(xv.y, w3.y, fmaf(xv.z, w3.z, fmaf(xv.w, w3.w, bv.w))));
    float4* orow = (float4*)out + (size_t)bt * (size_t)S * 128;
    for (int si = shalf; si < S; si += 2)
        orow[(size_t)si * 128 + d4] = y;
}

extern "C" void kernel_launch(void* const* d_in, const int* in_sizes, int n_in,
                              void* d_out, int out_size, void* d_ws, size_t ws_size,
                              hipStream_t stream) {
    const float* x    = (const float*)d_in[0];   // [B,T,4] fp32
    const float* W    = (const float*)d_in[2];   // [512,4] fp32
    const float* bias = (const float*)d_in[3];   // [512]   fp32
    float* out        = (float*)d_out;

    const int BT = in_sizes[0] / D_INP;               // 3072
    const int S  = out_size / (BT * D_MODEL);         // 64
    const size_t N4 = (size_t)out_size / 4;           // float4 count

    if ((S & (S - 1)) == 0) {
        // btShift = log2(S * 128): S=64 -> 13
        int btShift = 0, v = S * (D_MODEL / 4);
        while ((1 << (btShift + 1)) <= v) ++btShift;
        // G=2048: 8 blocks/CU fully resident; stride 2048*256=524288 float4,
        // divisible by S*128=8192 -> (s,d4) invariant per thread.
        tfe_flat<<<2048, 256, 0, stream>>>(
            (const float4*)x, (const float4*)W, (const float4*)bias,
            (float4*)out, N4, btShift);
    } else {
        tfe_embed_bcast<<<BT, 256, 0, stream>>>(x, W, bias, out, S);
    }
}